// Round 5
// baseline (576.258 us; speedup 1.0000x reference)
//
#include <hip/hip_runtime.h>
#include <hip/hip_bf16.h>
#include <math.h>
#include <stdint.h>

typedef unsigned int u32;
typedef unsigned long long u64;

#define NROWS 16384
#define KCB   2048
#define DIMS  256

// ---------------- threefry2x32-20, key = (0, 42)  (jax.random.key(42)) ----
__device__ __forceinline__ u32 rotl32(u32 x, int r) { return (x << r) | (x >> (32 - r)); }

__device__ __forceinline__ uint2 threefry42(u32 x0, u32 x1) {
  const u32 ks0 = 0u, ks1 = 42u, ks2 = 0x1BD11BDAu ^ 42u;
  x0 += ks0; x1 += ks1;
  x0 += x1; x1 = rotl32(x1, 13); x1 ^= x0;
  x0 += x1; x1 = rotl32(x1, 15); x1 ^= x0;
  x0 += x1; x1 = rotl32(x1, 26); x1 ^= x0;
  x0 += x1; x1 = rotl32(x1, 6);  x1 ^= x0;
  x0 += ks1; x1 += ks2 + 1u;
  x0 += x1; x1 = rotl32(x1, 17); x1 ^= x0;
  x0 += x1; x1 = rotl32(x1, 29); x1 ^= x0;
  x0 += x1; x1 = rotl32(x1, 16); x1 ^= x0;
  x0 += x1; x1 = rotl32(x1, 24); x1 ^= x0;
  x0 += ks2; x1 += ks0 + 2u;
  x0 += x1; x1 = rotl32(x1, 13); x1 ^= x0;
  x0 += x1; x1 = rotl32(x1, 15); x1 ^= x0;
  x0 += x1; x1 = rotl32(x1, 26); x1 ^= x0;
  x0 += x1; x1 = rotl32(x1, 6);  x1 ^= x0;
  x0 += ks0; x1 += ks1 + 3u;
  x0 += x1; x1 = rotl32(x1, 17); x1 ^= x0;
  x0 += x1; x1 = rotl32(x1, 29); x1 ^= x0;
  x0 += x1; x1 = rotl32(x1, 16); x1 ^= x0;
  x0 += x1; x1 = rotl32(x1, 24); x1 ^= x0;
  x0 += ks1; x1 += ks2 + 4u;
  x0 += x1; x1 = rotl32(x1, 13); x1 ^= x0;
  x0 += x1; x1 = rotl32(x1, 15); x1 ^= x0;
  x0 += x1; x1 = rotl32(x1, 26); x1 ^= x0;
  x0 += x1; x1 = rotl32(x1, 6);  x1 ^= x0;
  x0 += ks2; x1 += ks0 + 5u;
  return make_uint2(x0, x1);
}

// partitionable threefry: counter = (0, i); bits = out0 ^ out1
__device__ __forceinline__ u32 tf_bits_partitionable(u32 i) {
  uint2 y = threefry42(0u, i);
  return y.x ^ y.y;
}

// jax uniform(minval=FLT_MIN,maxval=1) then gumbel = -log(-log(u)), fp32
__device__ __forceinline__ float gumbel_from_bits(u32 bits) {
  float u = __uint_as_float((bits >> 9) | 0x3f800000u) - 1.0f;
  u = (u == 0.0f) ? 1.17549435082228751e-38f : u;
  return -logf(-logf(u));
}

// numpy pairwise sum-of-squares for 128 contiguous floats (8-acc unrolled)
__device__ __forceinline__ float np_pairwise_sq128(const float* __restrict__ a) {
  float r0 = 0.f, r1 = 0.f, r2 = 0.f, r3 = 0.f, r4 = 0.f, r5 = 0.f, r6 = 0.f, r7 = 0.f;
  for (int i = 0; i < 128; i += 8) {
    r0 = __fadd_rn(r0, __fmul_rn(a[i + 0], a[i + 0]));
    r1 = __fadd_rn(r1, __fmul_rn(a[i + 1], a[i + 1]));
    r2 = __fadd_rn(r2, __fmul_rn(a[i + 2], a[i + 2]));
    r3 = __fadd_rn(r3, __fmul_rn(a[i + 3], a[i + 3]));
    r4 = __fadd_rn(r4, __fmul_rn(a[i + 4], a[i + 4]));
    r5 = __fadd_rn(r5, __fmul_rn(a[i + 5], a[i + 5]));
    r6 = __fadd_rn(r6, __fmul_rn(a[i + 6], a[i + 6]));
    r7 = __fadd_rn(r7, __fmul_rn(a[i + 7], a[i + 7]));
  }
  return __fadd_rn(__fadd_rn(__fadd_rn(r0, r1), __fadd_rn(r2, r3)),
                   __fadd_rn(__fadd_rn(r4, r5), __fadd_rn(r6, r7)));
}
__device__ __forceinline__ float np_pairwise_sq256(const float* __restrict__ a) {
  return __fadd_rn(np_pairwise_sq128(a), np_pairwise_sq128(a + 128));
}

// ---------------- k_rowstats: A_n = sum x^2 (pairwise order) ------------
__global__ __launch_bounds__(256) void k_rowstats(const float* __restrict__ flat,
                                                  float* __restrict__ rowA,
                                                  float* __restrict__ rnorm) {
  int n = blockIdx.x * 256 + threadIdx.x;   // grid 64 -> 16384 threads
  const float* p = flat + (size_t)n * DIMS;
  float acc = np_pairwise_sq256(p);
  rowA[n] = acc;
  rnorm[n] = sqrtf(acc);
}

// ---------------- k_codestats: repar = mean + std*cb; sqk pairwise ------
// also zero-inits hist and idx (merged k_init)
__global__ __launch_bounds__(64) void k_codestats(const float* __restrict__ cb,
                                                  const float* __restrict__ cmean,
                                                  const float* __restrict__ cstd,
                                                  float* __restrict__ repar,
                                                  float* __restrict__ sqk,
                                                  float* __restrict__ ncn,
                                                  int* __restrict__ hist,
                                                  int* __restrict__ idx) {
  __shared__ float row[DIMS];
  int k = blockIdx.x;
  int lane = threadIdx.x;
  int gid = k * 64 + lane;            // 0..131071
  if (gid < KCB) hist[gid] = 0;
  if (gid < NROWS) idx[gid] = 0;
  float4 c = ((const float4*)(cb + (size_t)k * DIMS))[lane];
  float4 m = ((const float4*)cmean)[lane];
  float4 sd = ((const float4*)cstd)[lane];
  float4 r;
  r.x = __fadd_rn(m.x, __fmul_rn(sd.x, c.x));
  r.y = __fadd_rn(m.y, __fmul_rn(sd.y, c.y));
  r.z = __fadd_rn(m.z, __fmul_rn(sd.z, c.z));
  r.w = __fadd_rn(m.w, __fmul_rn(sd.w, c.w));
  ((float4*)(repar + (size_t)k * DIMS))[lane] = r;
  ((float4*)row)[lane] = r;
  __syncthreads();
  if (lane == 0) {
    float acc = np_pairwise_sq256(row);
    sqk[k] = acc;
    ncn[k] = sqrtf(acc);
  }
}

// ---------------- k_main: fused GEMM + gumbel argmax --------------------
// 512 threads: half h handles column chunks h*8..h*8+7. 32x128 tile per
// half per chunk, 4x4 microtile, BK=32. LDS exactly 64 KB.
#define BM 32
#define BN 128
#define BKD 32

__global__ __launch_bounds__(512) void k_main(const float* __restrict__ flat,
                                              const float* __restrict__ repar,
                                              const float* __restrict__ rowA,
                                              const float* __restrict__ sqk,
                                              int* __restrict__ idx_out,
                                              float* __restrict__ out_idx) {
  __shared__ float At[DIMS][BM];        // 32 KB; reads are wave-broadcast b128
  __shared__ float Bs[2][BKD][BN];      // 32 KB (one buffer per half)

  const int t = threadIdx.x;            // 0..511
  const int h = t >> 8;                 // half 0/1
  const int tl = t & 255;
  const int ty = tl >> 5;               // 0..7  -> rows 4*ty..4*ty+3
  const int tx = tl & 31;               // 0..31 -> cols 4*tx..4*tx+3
  const int r0 = blockIdx.x * BM;

  // stage A transposed (once). r=t&31: LDS writes 2-way (free); each thread
  // reads one full 64B line of flat (no overfetch).
  {
    int r = t & 31;
    int dseg = (t >> 5) * 16;           // 0..240
    const float4* src = (const float4*)(flat + (size_t)(r0 + r) * DIMS + dseg);
#pragma unroll
    for (int j = 0; j < 4; ++j) {
      float4 v = src[j];
      int d = dseg + 4 * j;
      At[d + 0][r] = v.x; At[d + 1][r] = v.y; At[d + 2][r] = v.z; At[d + 3][r] = v.w;
    }
  }

  float An[4];
#pragma unroll
  for (int i = 0; i < 4; ++i) An[i] = rowA[r0 + 4 * ty + i];

  float bestv[4];
  int bestk[4];
#pragma unroll
  for (int i = 0; i < 4; ++i) { bestv[i] = -3.4e38f; bestk[i] = 0; }

  for (int cc = 0; cc < 8; ++cc) {      // 8 chunks per half
    const int c0 = (h * 8 + cc) * BN;
    float acc[4][4] = {{0.f, 0.f, 0.f, 0.f}, {0.f, 0.f, 0.f, 0.f},
                       {0.f, 0.f, 0.f, 0.f}, {0.f, 0.f, 0.f, 0.f}};
    for (int dc = 0; dc < DIMS / BKD; ++dc) {  // 8
      const int d0 = dc * BKD;
      __syncthreads();
      {
        int c = tl & 127;
        int dh = (tl >> 7) * 16;  // 0 or 16
        const float4* src = (const float4*)(repar + (size_t)(c0 + c) * DIMS + d0 + dh);
#pragma unroll
        for (int j = 0; j < 4; ++j) {
          float4 v = src[j];
          int d = dh + 4 * j;
          Bs[h][d + 0][c] = v.x; Bs[h][d + 1][c] = v.y;
          Bs[h][d + 2][c] = v.z; Bs[h][d + 3][c] = v.w;
        }
      }
      __syncthreads();
#pragma unroll 8
      for (int d = 0; d < BKD; ++d) {
        float4 a = *(const float4*)&At[d0 + d][4 * ty];
        float4 b = *(const float4*)&Bs[h][d][4 * tx];
        float av[4] = {a.x, a.y, a.z, a.w};
        float bv[4] = {b.x, b.y, b.z, b.w};
#pragma unroll
        for (int i = 0; i < 4; ++i)
#pragma unroll
          for (int j = 0; j < 4; ++j) acc[i][j] += av[i] * bv[j];
      }
    }
    // epilogue: v = g - ((A - 2b) + C)  (matches ref op order)
    float4 sqv = *(const float4*)(sqk + c0 + 4 * tx);
    float sqa[4] = {sqv.x, sqv.y, sqv.z, sqv.w};
#pragma unroll
    for (int i = 0; i < 4; ++i) {
      const u32 n = (u32)(r0 + 4 * ty + i);
      const u32 base = n * 2048u + (u32)(c0 + 4 * tx);
#pragma unroll
      for (int j = 0; j < 4; ++j) {
        float t3 = __fsub_rn(An[i], __fmul_rn(2.0f, acc[i][j]));
        float t4 = __fadd_rn(t3, sqa[j]);
        u32 bits = tf_bits_partitionable(base + (u32)j);
        float g = gumbel_from_bits(bits);
        float v = __fsub_rn(g, t4);
        int kk = (int)(c0 + 4 * tx + (u32)j);
        if (v > bestv[i] || (v == bestv[i] && kk < bestk[i])) { bestv[i] = v; bestk[i] = kk; }
      }
    }
  }

  // cross-lane argmax per row within each half (32 tx lanes share (h,ty))
#pragma unroll
  for (int i = 0; i < 4; ++i) {
#pragma unroll
    for (int m = 1; m < 32; m <<= 1) {
      float ov = __shfl_xor(bestv[i], m);
      int ok = __shfl_xor(bestk[i], m);
      if (ov > bestv[i] || (ov == bestv[i] && ok < bestk[i])) {
        bestv[i] = ov; bestk[i] = ok;
      }
    }
  }

  // combine halves via LDS aliased into Bs (all Bs reads done after barrier)
  float* redv = (float*)&Bs[0][0][0];     // 64 floats
  int*   redk = (int*)&Bs[0][0][0] + 64;  // 64 ints
  __syncthreads();
  if (tx == 0) {
#pragma unroll
    for (int i = 0; i < 4; ++i) {
      int rr = 4 * ty + i;
      redv[h * 32 + rr] = bestv[i];
      redk[h * 32 + rr] = bestk[i];
    }
  }
  __syncthreads();
  if (t < 32) {
    float v0 = redv[t];      int k0 = redk[t];
    float v1 = redv[32 + t]; int k1 = redk[32 + t];
    bool take1 = (v1 > v0) || (v1 == v0 && k1 < k0);
    float v = take1 ? v1 : v0;
    int   k = take1 ? k1 : k0;
    (void)v;
    idx_out[r0 + t] = k;
    out_idx[r0 + t] = (float)k;
  }
}

// ---------------- k_quant: write quantized (STE), mse/cos, hist ---------
__global__ __launch_bounds__(256) void k_quant(const float* __restrict__ flat,
                                               const float* __restrict__ repar,
                                               const int* __restrict__ idx,
                                               const float* __restrict__ rnorm,
                                               const float* __restrict__ ncn,
                                               float* __restrict__ outq,
                                               double* __restrict__ qp_mse,
                                               double* __restrict__ qp_cos,
                                               int* __restrict__ hist) {
  int t = threadIdx.x, w = t >> 6, lane = t & 63;
  int n = blockIdx.x * 4 + w;
  int k = idx[n];
  k = (k < 0) ? 0 : (k > (KCB - 1) ? (KCB - 1) : k);   // defensive clamp
  float4 q = ((const float4*)(repar + (size_t)k * DIMS))[lane];
  float4 x = ((const float4*)(flat + (size_t)n * DIMS))[lane];
  // STE forward value: fl(x + fl(q - x))
  float4 qo;
  qo.x = __fadd_rn(x.x, __fsub_rn(q.x, x.x));
  qo.y = __fadd_rn(x.y, __fsub_rn(q.y, x.y));
  qo.z = __fadd_rn(x.z, __fsub_rn(q.z, x.z));
  qo.w = __fadd_rn(x.w, __fsub_rn(q.w, x.w));
  ((float4*)(outq + (size_t)n * DIMS))[lane] = qo;
  float dx = x.x - qo.x, dy = x.y - qo.y, dz = x.z - qo.z, dw = x.w - qo.w;
  float dd = dx * dx + dy * dy + dz * dz + dw * dw;
  float dot = x.x * q.x + x.y * q.y + x.z * q.z + x.w * q.w;
#pragma unroll
  for (int m = 1; m < 64; m <<= 1) { dd += __shfl_xor(dd, m); dot += __shfl_xor(dot, m); }
  __shared__ double sm[4], sc[4];
  if (lane == 0) {
    sm[w] = (double)dd;
    float cs = dot / (fmaxf(rnorm[n], 1e-12f) * fmaxf(ncn[k], 1e-12f));
    sc[w] = (double)cs;
    atomicAdd(&hist[k], 1);
  }
  __syncthreads();
  if (t == 0) {
    qp_mse[blockIdx.x] = sm[0] + sm[1] + sm[2] + sm[3];
    qp_cos[blockIdx.x] = sc[0] + sc[1] + sc[2] + sc[3];
  }
}

// ---------------- k_pairs: codebook pairwise distances ------------------
#define PBK 32
__global__ __launch_bounds__(256) void k_pairs(const float* __restrict__ repar,
                                               const float* __restrict__ sqk,
                                               double* __restrict__ pp_sum,
                                               u32* __restrict__ pp_min) {
  __shared__ float Ci[PBK][64 + 4];
  __shared__ float Cj[PBK][64 + 4];
  const int t = threadIdx.x;
  const int ty = t >> 4;   // 0..15
  const int tx = t & 15;   // 0..15
  const int i0 = blockIdx.x * 64, j0 = blockIdx.y * 64;
  float acc[4][4] = {{0.f, 0.f, 0.f, 0.f}, {0.f, 0.f, 0.f, 0.f},
                     {0.f, 0.f, 0.f, 0.f}, {0.f, 0.f, 0.f, 0.f}};
  for (int dc = 0; dc < DIMS / PBK; ++dc) {
    __syncthreads();
    {
      int r = t >> 2;           // 0..63
      int ds = (t & 3) * 8;     // 0,8,16,24
      const float4* si = (const float4*)(repar + (size_t)(i0 + r) * DIMS + dc * PBK + ds);
      float4 a0 = si[0], a1 = si[1];
      const float4* sj = (const float4*)(repar + (size_t)(j0 + r) * DIMS + dc * PBK + ds);
      float4 b0 = sj[0], b1 = sj[1];
      Ci[ds + 0][r] = a0.x; Ci[ds + 1][r] = a0.y; Ci[ds + 2][r] = a0.z; Ci[ds + 3][r] = a0.w;
      Ci[ds + 4][r] = a1.x; Ci[ds + 5][r] = a1.y; Ci[ds + 6][r] = a1.z; Ci[ds + 7][r] = a1.w;
      Cj[ds + 0][r] = b0.x; Cj[ds + 1][r] = b0.y; Cj[ds + 2][r] = b0.z; Cj[ds + 3][r] = b0.w;
      Cj[ds + 4][r] = b1.x; Cj[ds + 5][r] = b1.y; Cj[ds + 6][r] = b1.z; Cj[ds + 7][r] = b1.w;
    }
    __syncthreads();
#pragma unroll 8
    for (int d = 0; d < PBK; ++d) {
      float4 a = *(const float4*)&Ci[d][4 * ty];
      float4 b = *(const float4*)&Cj[d][4 * tx];
      float av[4] = {a.x, a.y, a.z, a.w};
      float bv[4] = {b.x, b.y, b.z, b.w};
#pragma unroll
      for (int i = 0; i < 4; ++i)
#pragma unroll
        for (int j = 0; j < 4; ++j) acc[i][j] += av[i] * bv[j];
    }
  }
  float4 s4i = *(const float4*)(sqk + i0 + 4 * ty);
  float4 s4j = *(const float4*)(sqk + j0 + 4 * tx);
  float sqi[4] = {s4i.x, s4i.y, s4i.z, s4i.w};
  float sqj[4] = {s4j.x, s4j.y, s4j.z, s4j.w};
  double lsum = 0.0;
  float lmin = 3.4e38f;
#pragma unroll
  for (int i = 0; i < 4; ++i)
#pragma unroll
    for (int j = 0; j < 4; ++j) {
      int gi = i0 + 4 * ty + i, gj = j0 + 4 * tx + j;
      if (gi != gj) {
        float d2 = fmaxf((sqi[i] + sqj[j]) - 2.0f * acc[i][j], 0.0f);
        float dd = sqrtf(d2);
        lsum += (double)dd;
        lmin = fminf(lmin, dd);
      }
    }
  int lane = t & 63, w = t >> 6;
#pragma unroll
  for (int m = 1; m < 64; m <<= 1) {
    lsum += __shfl_xor(lsum, m);
    lmin = fminf(lmin, __shfl_xor(lmin, m));
  }
  __shared__ double sps[4];
  __shared__ float spm[4];
  if (lane == 0) { sps[w] = lsum; spm[w] = lmin; }
  __syncthreads();
  if (t == 0) {
    int bid = blockIdx.y * gridDim.x + blockIdx.x;
    pp_sum[bid] = sps[0] + sps[1] + sps[2] + sps[3];
    pp_min[bid] = __float_as_uint(fminf(fminf(spm[0], spm[1]), fminf(spm[2], spm[3])));
  }
}

// ---------------- k_final: scalars --------------------------------------
__global__ __launch_bounds__(256) void k_final(const double* __restrict__ qp_mse,
                                               const double* __restrict__ qp_cos,
                                               const double* __restrict__ pp_sum,
                                               const u32* __restrict__ pp_min,
                                               const int* __restrict__ hist,
                                               float* __restrict__ outs) {
  int t = threadIdx.x;
  double lm = 0, lc = 0, ld = 0, lH = 0;
  float lmin = 3.4e38f;
  for (int j = 0; j < 16; ++j) { lm += qp_mse[t + 256 * j]; lc += qp_cos[t + 256 * j]; }
  for (int j = 0; j < 4; ++j) {
    ld += pp_sum[t + 256 * j];
    lmin = fminf(lmin, __uint_as_float(pp_min[t + 256 * j]));
  }
  for (int k = t; k < KCB; k += 256) {
    float p = (float)hist[k] * (1.0f / 16384.0f);
    lH -= (double)(p * logf(p + 1e-10f));
  }
  __shared__ double sh[256];
  double mse, cosS, dS, H, mn;
  sh[t] = lm; __syncthreads();
  for (int s = 128; s; s >>= 1) { if (t < s) sh[t] += sh[t + s]; __syncthreads(); }
  mse = sh[0]; __syncthreads();
  sh[t] = lc; __syncthreads();
  for (int s = 128; s; s >>= 1) { if (t < s) sh[t] += sh[t + s]; __syncthreads(); }
  cosS = sh[0]; __syncthreads();
  sh[t] = ld; __syncthreads();
  for (int s = 128; s; s >>= 1) { if (t < s) sh[t] += sh[t + s]; __syncthreads(); }
  dS = sh[0]; __syncthreads();
  sh[t] = lH; __syncthreads();
  for (int s = 128; s; s >>= 1) { if (t < s) sh[t] += sh[t + s]; __syncthreads(); }
  H = sh[0]; __syncthreads();
  sh[t] = (double)lmin; __syncthreads();
  for (int s = 128; s; s >>= 1) { if (t < s) sh[t] = fmin(sh[t], sh[t + s]); __syncthreads(); }
  mn = sh[0];
  if (t == 0) {
    double meansq = mse / 4194304.0;
    outs[0] = (float)(0.25 * meansq);          // commitment_loss
    outs[1] = (float)meansq;                   // codebook_loss
    outs[2] = (float)exp(H);                   // perplexity
    outs[3] = (float)(cosS / 16384.0);         // selected_cosine_sim
    outs[4] = (float)(dS / (2048.0 * 2047.0)); // avg_euclidean
    outs[5] = (float)mn;                       // min_euclidean
    outs[6] = (float)sqrt(mse);                // gradient_gap
  }
}

// ---------------- launch -------------------------------------------------
extern "C" void kernel_launch(void* const* d_in, const int* in_sizes, int n_in,
                              void* d_out, int out_size, void* d_ws, size_t ws_size,
                              hipStream_t stream) {
  (void)in_sizes; (void)n_in; (void)out_size; (void)ws_size;
  const float* latent  = (const float*)d_in[0];
  const float* cb      = (const float*)d_in[1];
  const float* cmean   = (const float*)d_in[2];
  const float* cstd    = (const float*)d_in[3];
  float* out           = (float*)d_out;     // reference outputs are float32

  char* ws = (char*)d_ws;
  float* repar  = (float*)(ws + 0);
  float* rowA   = (float*)(ws + 2097152);
  float* rnorm  = (float*)(ws + 2162688);
  float* sqk    = (float*)(ws + 2228224);
  float* ncn    = (float*)(ws + 2236416);
  int*   idx    = (int*)(ws + 2244608);
  int*   hist   = (int*)(ws + 2310144);
  double* qp_mse = (double*)(ws + 2318336);
  double* qp_cos = (double*)(ws + 2351104);
  double* pp_sum = (double*)(ws + 2383872);
  u32*    pp_min = (u32*)(ws + 2392064);

  float* out_q   = out;               // 4194304 floats
  float* out_idx = out + 4194304;     // 16384 floats
  float* out_scl = out + 4210688;     // 7 floats

  k_rowstats<<<64, 256, 0, stream>>>(latent, rowA, rnorm);
  k_codestats<<<KCB, 64, 0, stream>>>(cb, cmean, cstd, repar, sqk, ncn, hist, idx);
  k_main<<<NROWS / BM, 512, 0, stream>>>(latent, repar, rowA, sqk, idx, out_idx);
  k_quant<<<NROWS / 4, 256, 0, stream>>>(latent, repar, idx, rnorm, ncn, out_q,
                                         qp_mse, qp_cos, hist);
  k_pairs<<<dim3(32, 32), 256, 0, stream>>>(repar, sqk, pp_sum, pp_min);
  k_final<<<1, 256, 0, stream>>>(qp_mse, qp_cos, pp_sum, pp_min, hist, out_scl);
}

// Round 6
// 287.907 us; speedup vs baseline: 2.0015x; 2.0015x over previous
//
#include <hip/hip_runtime.h>
#include <hip/hip_bf16.h>
#include <math.h>
#include <stdint.h>

typedef unsigned int u32;
typedef unsigned long long u64;
typedef __attribute__((ext_vector_type(8))) short bf16x8;
typedef __attribute__((ext_vector_type(4))) float f32x4;

#define NROWS 16384
#define KCB   2048
#define DIMS  256

// ---------------- threefry2x32-20, key = (0, 42)  (jax.random.key(42)) ----
__device__ __forceinline__ u32 rotl32(u32 x, int r) { return (x << r) | (x >> (32 - r)); }

__device__ __forceinline__ uint2 threefry42(u32 x0, u32 x1) {
  const u32 ks0 = 0u, ks1 = 42u, ks2 = 0x1BD11BDAu ^ 42u;
  x0 += ks0; x1 += ks1;
  x0 += x1; x1 = rotl32(x1, 13); x1 ^= x0;
  x0 += x1; x1 = rotl32(x1, 15); x1 ^= x0;
  x0 += x1; x1 = rotl32(x1, 26); x1 ^= x0;
  x0 += x1; x1 = rotl32(x1, 6);  x1 ^= x0;
  x0 += ks1; x1 += ks2 + 1u;
  x0 += x1; x1 = rotl32(x1, 17); x1 ^= x0;
  x0 += x1; x1 = rotl32(x1, 29); x1 ^= x0;
  x0 += x1; x1 = rotl32(x1, 16); x1 ^= x0;
  x0 += x1; x1 = rotl32(x1, 24); x1 ^= x0;
  x0 += ks2; x1 += ks0 + 2u;
  x0 += x1; x1 = rotl32(x1, 13); x1 ^= x0;
  x0 += x1; x1 = rotl32(x1, 15); x1 ^= x0;
  x0 += x1; x1 = rotl32(x1, 26); x1 ^= x0;
  x0 += x1; x1 = rotl32(x1, 6);  x1 ^= x0;
  x0 += ks0; x1 += ks1 + 3u;
  x0 += x1; x1 = rotl32(x1, 17); x1 ^= x0;
  x0 += x1; x1 = rotl32(x1, 29); x1 ^= x0;
  x0 += x1; x1 = rotl32(x1, 16); x1 ^= x0;
  x0 += x1; x1 = rotl32(x1, 24); x1 ^= x0;
  x0 += ks1; x1 += ks2 + 4u;
  x0 += x1; x1 = rotl32(x1, 13); x1 ^= x0;
  x0 += x1; x1 = rotl32(x1, 15); x1 ^= x0;
  x0 += x1; x1 = rotl32(x1, 26); x1 ^= x0;
  x0 += x1; x1 = rotl32(x1, 6);  x1 ^= x0;
  x0 += ks2; x1 += ks0 + 5u;
  return make_uint2(x0, x1);
}

// partitionable threefry: counter = (0, i); bits = out0 ^ out1
__device__ __forceinline__ u32 tf_bits_partitionable(u32 i) {
  uint2 y = threefry42(0u, i);
  return y.x ^ y.y;
}

// jax uniform(minval=FLT_MIN,maxval=1) then gumbel = -log(-log(u)), fp32
__device__ __forceinline__ float gumbel_from_bits(u32 bits) {
  float u = __uint_as_float((bits >> 9) | 0x3f800000u) - 1.0f;
  u = (u == 0.0f) ? 1.17549435082228751e-38f : u;
  return -logf(-logf(u));
}

__device__ __forceinline__ short f2bf_s(float f) {
  union { __hip_bfloat16 h; short s; } cv; cv.h = __float2bfloat16(f); return cv.s;
}
__device__ __forceinline__ float bfs2f(short s) {
  union { __hip_bfloat16 h; short s2; } cv; cv.s2 = s; return __bfloat162float(cv.h);
}

// numpy pairwise sum-of-squares for 128 contiguous floats (8-acc unrolled)
__device__ __forceinline__ float np_pairwise_sq128(const float* __restrict__ a) {
  float r0 = 0.f, r1 = 0.f, r2 = 0.f, r3 = 0.f, r4 = 0.f, r5 = 0.f, r6 = 0.f, r7 = 0.f;
  for (int i = 0; i < 128; i += 8) {
    r0 = __fadd_rn(r0, __fmul_rn(a[i + 0], a[i + 0]));
    r1 = __fadd_rn(r1, __fmul_rn(a[i + 1], a[i + 1]));
    r2 = __fadd_rn(r2, __fmul_rn(a[i + 2], a[i + 2]));
    r3 = __fadd_rn(r3, __fmul_rn(a[i + 3], a[i + 3]));
    r4 = __fadd_rn(r4, __fmul_rn(a[i + 4], a[i + 4]));
    r5 = __fadd_rn(r5, __fmul_rn(a[i + 5], a[i + 5]));
    r6 = __fadd_rn(r6, __fmul_rn(a[i + 6], a[i + 6]));
    r7 = __fadd_rn(r7, __fmul_rn(a[i + 7], a[i + 7]));
  }
  return __fadd_rn(__fadd_rn(__fadd_rn(r0, r1), __fadd_rn(r2, r3)),
                   __fadd_rn(__fadd_rn(r4, r5), __fadd_rn(r6, r7)));
}
__device__ __forceinline__ float np_pairwise_sq256(const float* __restrict__ a) {
  return __fadd_rn(np_pairwise_sq128(a), np_pairwise_sq128(a + 128));
}

// ---------------- k_rowstats ------------------------------------------- 
__global__ __launch_bounds__(256) void k_rowstats(const float* __restrict__ flat,
                                                  float* __restrict__ rowA,
                                                  float* __restrict__ rnorm) {
  int n = blockIdx.x * 256 + threadIdx.x;
  const float* p = flat + (size_t)n * DIMS;
  float acc = np_pairwise_sq256(p);
  rowA[n] = acc;
  rnorm[n] = sqrtf(acc);
}

// ---------------- k_codestats: repar, sqk; init hist + row_max ----------
__global__ __launch_bounds__(64) void k_codestats(const float* __restrict__ cb,
                                                  const float* __restrict__ cmean,
                                                  const float* __restrict__ cstd,
                                                  float* __restrict__ repar,
                                                  float* __restrict__ sqk,
                                                  float* __restrict__ ncn,
                                                  int* __restrict__ hist,
                                                  u64* __restrict__ row_max) {
  __shared__ float row[DIMS];
  int k = blockIdx.x;
  int lane = threadIdx.x;
  int gid = k * 64 + lane;
  if (gid < KCB) hist[gid] = 0;
  if (gid < NROWS) row_max[gid] = 0ull;
  float4 c = ((const float4*)(cb + (size_t)k * DIMS))[lane];
  float4 m = ((const float4*)cmean)[lane];
  float4 sd = ((const float4*)cstd)[lane];
  float4 r;
  r.x = __fadd_rn(m.x, __fmul_rn(sd.x, c.x));
  r.y = __fadd_rn(m.y, __fmul_rn(sd.y, c.y));
  r.z = __fadd_rn(m.z, __fmul_rn(sd.z, c.z));
  r.w = __fadd_rn(m.w, __fmul_rn(sd.w, c.w));
  ((float4*)(repar + (size_t)k * DIMS))[lane] = r;
  ((float4*)row)[lane] = r;
  __syncthreads();
  if (lane == 0) {
    float acc = np_pairwise_sq256(row);
    sqk[k] = acc;
    ncn[k] = sqrtf(acc);
  }
}

// ---------------- k_main: bf16-split MFMA GEMM + gumbel argmax ----------
// block: 64 rows x 64 cols, 256 thr = 4 waves x 4 (16x16) tiles.
// grid (32 colblk [x, fastest], 256 rowblk [y]) for A L2 reuse.
__global__ __launch_bounds__(256) void k_main(const float* __restrict__ flat,
                                              const float* __restrict__ repar,
                                              const float* __restrict__ rowA,
                                              const float* __restrict__ sqk,
                                              u64* __restrict__ row_max) {
  __shared__ short AsH[64][40], AsL[64][40], BsH[64][40], BsL[64][40];  // 20 KB

  const int t = threadIdx.x;
  const int wid = t >> 6, lane = t & 63;
  const int r = lane & 15, q = lane >> 4;
  const int r0 = blockIdx.y * 64;
  const int c0 = blockIdx.x * 64;

  const int srow = t >> 2;          // 0..63
  const int sd   = (t & 3) * 8;     // 0,8,16,24

  f32x4 acc[4] = {{0.f,0.f,0.f,0.f},{0.f,0.f,0.f,0.f},
                  {0.f,0.f,0.f,0.f},{0.f,0.f,0.f,0.f}};

  for (int sl = 0; sl < 8; ++sl) {
    const int d0 = sl * 32;
    __syncthreads();
    // stage A rows (64x32 fp32 -> hi/lo bf16) and B cols (64x32) symmetrically
    {
      const float* ap = flat + (size_t)(r0 + srow) * DIMS + d0 + sd;
      float4 a0 = ((const float4*)ap)[0];
      float4 a1 = ((const float4*)ap)[1];
      float av[8] = {a0.x, a0.y, a0.z, a0.w, a1.x, a1.y, a1.z, a1.w};
      bf16x8 vh, vl;
#pragma unroll
      for (int j = 0; j < 8; ++j) {
        float x = av[j];
        short h = f2bf_s(x);
        vh[j] = h;
        vl[j] = f2bf_s(__fsub_rn(x, bfs2f(h)));
      }
      *(bf16x8*)&AsH[srow][sd] = vh;
      *(bf16x8*)&AsL[srow][sd] = vl;

      const float* bp = repar + (size_t)(c0 + srow) * DIMS + d0 + sd;
      float4 b0 = ((const float4*)bp)[0];
      float4 b1 = ((const float4*)bp)[1];
      float bv[8] = {b0.x, b0.y, b0.z, b0.w, b1.x, b1.y, b1.z, b1.w};
      bf16x8 wh, wl;
#pragma unroll
      for (int j = 0; j < 8; ++j) {
        float x = bv[j];
        short h = f2bf_s(x);
        wh[j] = h;
        wl[j] = f2bf_s(__fsub_rn(x, bfs2f(h)));
      }
      *(bf16x8*)&BsH[srow][sd] = wh;
      *(bf16x8*)&BsL[srow][sd] = wl;
    }
    __syncthreads();
    // A-frag: A[m=lane&15][k=q*8+j]; B-frag: B[k=q*8+j][n=lane&15]
    bf16x8 ah = *(const bf16x8*)&AsH[wid * 16 + r][q * 8];
    bf16x8 al = *(const bf16x8*)&AsL[wid * 16 + r][q * 8];
#pragma unroll
    for (int tile = 0; tile < 4; ++tile) {
      bf16x8 bh = *(const bf16x8*)&BsH[tile * 16 + r][q * 8];
      bf16x8 bl = *(const bf16x8*)&BsL[tile * 16 + r][q * 8];
      acc[tile] = __builtin_amdgcn_mfma_f32_16x16x32_bf16(ah, bh, acc[tile], 0, 0, 0);
      acc[tile] = __builtin_amdgcn_mfma_f32_16x16x32_bf16(ah, bl, acc[tile], 0, 0, 0);
      acc[tile] = __builtin_amdgcn_mfma_f32_16x16x32_bf16(al, bh, acc[tile], 0, 0, 0);
    }
  }

  // epilogue: C/D layout col=lane&15, row=q*4+reg
  const int nbase = r0 + wid * 16 + q * 4;
  float An[4];
#pragma unroll
  for (int reg = 0; reg < 4; ++reg) An[reg] = rowA[nbase + reg];
  float bv[4];
  int bk[4];
#pragma unroll
  for (int reg = 0; reg < 4; ++reg) { bv[reg] = -3.4e38f; bk[reg] = 0; }

#pragma unroll
  for (int tile = 0; tile < 4; ++tile) {
    int col = c0 + tile * 16 + r;
    float sqa = sqk[col];
#pragma unroll
    for (int reg = 0; reg < 4; ++reg) {
      float dot = acc[tile][reg];
      float t3 = __fsub_rn(An[reg], __fmul_rn(2.0f, dot));
      float t4 = __fadd_rn(t3, sqa);
      u32 bits = tf_bits_partitionable((u32)(nbase + reg) * 2048u + (u32)col);
      float g = gumbel_from_bits(bits);
      float v = __fsub_rn(g, t4);
      if (v > bv[reg] || (v == bv[reg] && col < bk[reg])) { bv[reg] = v; bk[reg] = col; }
    }
  }

  // reduce across the 16 col-lanes of each q-group, then one atomic per row
#pragma unroll
  for (int reg = 0; reg < 4; ++reg) {
#pragma unroll
    for (int m = 1; m < 16; m <<= 1) {
      float ov = __shfl_xor(bv[reg], m);
      int ok = __shfl_xor(bk[reg], m);
      if (ov > bv[reg] || (ov == bv[reg] && ok < bk[reg])) { bv[reg] = ov; bk[reg] = ok; }
    }
    if (r == 0) {
      u32 s = __float_as_uint(bv[reg]);
      u32 uo = (s & 0x80000000u) ? ~s : (s | 0x80000000u);
      u64 key = ((u64)uo << 32) | (u64)(u32)(2047 - bk[reg]);  // max v, then min k
      atomicMax(&row_max[nbase + reg], key);
    }
  }
}

// ---------------- k_argmax: unpack per-row winner -----------------------
__global__ __launch_bounds__(256) void k_argmax(const u64* __restrict__ row_max,
                                                int* __restrict__ idx_out,
                                                float* __restrict__ out_idx) {
  int n = blockIdx.x * 256 + threadIdx.x;
  u64 key = row_max[n];
  int k = 2047 - (int)(u32)(key & 0xFFFFFFFFull);
  idx_out[n] = k;
  out_idx[n] = (float)k;
}

// ---------------- k_quant: write quantized (STE), mse/cos, hist ---------
__global__ __launch_bounds__(256) void k_quant(const float* __restrict__ flat,
                                               const float* __restrict__ repar,
                                               const int* __restrict__ idx,
                                               const float* __restrict__ rnorm,
                                               const float* __restrict__ ncn,
                                               float* __restrict__ outq,
                                               double* __restrict__ qp_mse,
                                               double* __restrict__ qp_cos,
                                               int* __restrict__ hist) {
  int t = threadIdx.x, w = t >> 6, lane = t & 63;
  int n = blockIdx.x * 4 + w;
  int k = idx[n];
  k = (k < 0) ? 0 : (k > (KCB - 1) ? (KCB - 1) : k);   // defensive clamp
  float4 q = ((const float4*)(repar + (size_t)k * DIMS))[lane];
  float4 x = ((const float4*)(flat + (size_t)n * DIMS))[lane];
  float4 qo;
  qo.x = __fadd_rn(x.x, __fsub_rn(q.x, x.x));
  qo.y = __fadd_rn(x.y, __fsub_rn(q.y, x.y));
  qo.z = __fadd_rn(x.z, __fsub_rn(q.z, x.z));
  qo.w = __fadd_rn(x.w, __fsub_rn(q.w, x.w));
  ((float4*)(outq + (size_t)n * DIMS))[lane] = qo;
  float dx = x.x - qo.x, dy = x.y - qo.y, dz = x.z - qo.z, dw = x.w - qo.w;
  float dd = dx * dx + dy * dy + dz * dz + dw * dw;
  float dot = x.x * q.x + x.y * q.y + x.z * q.z + x.w * q.w;
#pragma unroll
  for (int m = 1; m < 64; m <<= 1) { dd += __shfl_xor(dd, m); dot += __shfl_xor(dot, m); }
  __shared__ double sm[4], sc[4];
  if (lane == 0) {
    sm[w] = (double)dd;
    float cs = dot / (fmaxf(rnorm[n], 1e-12f) * fmaxf(ncn[k], 1e-12f));
    sc[w] = (double)cs;
    atomicAdd(&hist[k], 1);
  }
  __syncthreads();
  if (t == 0) {
    qp_mse[blockIdx.x] = sm[0] + sm[1] + sm[2] + sm[3];
    qp_cos[blockIdx.x] = sc[0] + sc[1] + sc[2] + sc[3];
  }
}

// ---------------- k_pairs: codebook pairwise distances ------------------
#define PBK 32
__global__ __launch_bounds__(256) void k_pairs(const float* __restrict__ repar,
                                               const float* __restrict__ sqk,
                                               double* __restrict__ pp_sum,
                                               u32* __restrict__ pp_min) {
  __shared__ float Ci[PBK][64 + 4];
  __shared__ float Cj[PBK][64 + 4];
  const int t = threadIdx.x;
  const int ty = t >> 4;
  const int tx = t & 15;
  const int i0 = blockIdx.x * 64, j0 = blockIdx.y * 64;
  float acc[4][4] = {{0.f, 0.f, 0.f, 0.f}, {0.f, 0.f, 0.f, 0.f},
                     {0.f, 0.f, 0.f, 0.f}, {0.f, 0.f, 0.f, 0.f}};
  for (int dc = 0; dc < DIMS / PBK; ++dc) {
    __syncthreads();
    {
      int rr = t >> 2;
      int ds = (t & 3) * 8;
      const float4* si = (const float4*)(repar + (size_t)(i0 + rr) * DIMS + dc * PBK + ds);
      float4 a0 = si[0], a1 = si[1];
      const float4* sj = (const float4*)(repar + (size_t)(j0 + rr) * DIMS + dc * PBK + ds);
      float4 b0 = sj[0], b1 = sj[1];
      Ci[ds + 0][rr] = a0.x; Ci[ds + 1][rr] = a0.y; Ci[ds + 2][rr] = a0.z; Ci[ds + 3][rr] = a0.w;
      Ci[ds + 4][rr] = a1.x; Ci[ds + 5][rr] = a1.y; Ci[ds + 6][rr] = a1.z; Ci[ds + 7][rr] = a1.w;
      Cj[ds + 0][rr] = b0.x; Cj[ds + 1][rr] = b0.y; Cj[ds + 2][rr] = b0.z; Cj[ds + 3][rr] = b0.w;
      Cj[ds + 4][rr] = b1.x; Cj[ds + 5][rr] = b1.y; Cj[ds + 6][rr] = b1.z; Cj[ds + 7][rr] = b1.w;
    }
    __syncthreads();
#pragma unroll 8
    for (int d = 0; d < PBK; ++d) {
      float4 a = *(const float4*)&Ci[d][4 * ty];
      float4 b = *(const float4*)&Cj[d][4 * tx];
      float av[4] = {a.x, a.y, a.z, a.w};
      float bvv[4] = {b.x, b.y, b.z, b.w};
#pragma unroll
      for (int i = 0; i < 4; ++i)
#pragma unroll
        for (int j = 0; j < 4; ++j) acc[i][j] += av[i] * bvv[j];
    }
  }
  float4 s4i = *(const float4*)(sqk + i0 + 4 * ty);
  float4 s4j = *(const float4*)(sqk + j0 + 4 * tx);
  float sqi[4] = {s4i.x, s4i.y, s4i.z, s4i.w};
  float sqj[4] = {s4j.x, s4j.y, s4j.z, s4j.w};
  double lsum = 0.0;
  float lmin = 3.4e38f;
#pragma unroll
  for (int i = 0; i < 4; ++i)
#pragma unroll
    for (int j = 0; j < 4; ++j) {
      int gi = i0 + 4 * ty + i, gj = j0 + 4 * tx + j;
      if (gi != gj) {
        float d2 = fmaxf((sqi[i] + sqj[j]) - 2.0f * acc[i][j], 0.0f);
        float dd = sqrtf(d2);
        lsum += (double)dd;
        lmin = fminf(lmin, dd);
      }
    }
  int lane = t & 63, w = t >> 6;
#pragma unroll
  for (int m = 1; m < 64; m <<= 1) {
    lsum += __shfl_xor(lsum, m);
    lmin = fminf(lmin, __shfl_xor(lmin, m));
  }
  __shared__ double sps[4];
  __shared__ float spm[4];
  if (lane == 0) { sps[w] = lsum; spm[w] = lmin; }
  __syncthreads();
  if (t == 0) {
    int bid = blockIdx.y * gridDim.x + blockIdx.x;
    pp_sum[bid] = sps[0] + sps[1] + sps[2] + sps[3];
    pp_min[bid] = __float_as_uint(fminf(fminf(spm[0], spm[1]), fminf(spm[2], spm[3])));
  }
}

// ---------------- k_final: scalars --------------------------------------
__global__ __launch_bounds__(256) void k_final(const double* __restrict__ qp_mse,
                                               const double* __restrict__ qp_cos,
                                               const double* __restrict__ pp_sum,
                                               const u32* __restrict__ pp_min,
                                               const int* __restrict__ hist,
                                               float* __restrict__ outs) {
  int t = threadIdx.x;
  double lm = 0, lc = 0, ld = 0, lH = 0;
  float lmin = 3.4e38f;
  for (int j = 0; j < 16; ++j) { lm += qp_mse[t + 256 * j]; lc += qp_cos[t + 256 * j]; }
  for (int j = 0; j < 4; ++j) {
    ld += pp_sum[t + 256 * j];
    lmin = fminf(lmin, __uint_as_float(pp_min[t + 256 * j]));
  }
  for (int k = t; k < KCB; k += 256) {
    float p = (float)hist[k] * (1.0f / 16384.0f);
    lH -= (double)(p * logf(p + 1e-10f));
  }
  __shared__ double sh[256];
  double mse, cosS, dS, H, mn;
  sh[t] = lm; __syncthreads();
  for (int s = 128; s; s >>= 1) { if (t < s) sh[t] += sh[t + s]; __syncthreads(); }
  mse = sh[0]; __syncthreads();
  sh[t] = lc; __syncthreads();
  for (int s = 128; s; s >>= 1) { if (t < s) sh[t] += sh[t + s]; __syncthreads(); }
  cosS = sh[0]; __syncthreads();
  sh[t] = ld; __syncthreads();
  for (int s = 128; s; s >>= 1) { if (t < s) sh[t] += sh[t + s]; __syncthreads(); }
  dS = sh[0]; __syncthreads();
  sh[t] = lH; __syncthreads();
  for (int s = 128; s; s >>= 1) { if (t < s) sh[t] += sh[t + s]; __syncthreads(); }
  H = sh[0]; __syncthreads();
  sh[t] = (double)lmin; __syncthreads();
  for (int s = 128; s; s >>= 1) { if (t < s) sh[t] = fmin(sh[t], sh[t + s]); __syncthreads(); }
  mn = sh[0];
  if (t == 0) {
    double meansq = mse / 4194304.0;
    outs[0] = (float)(0.25 * meansq);          // commitment_loss
    outs[1] = (float)meansq;                   // codebook_loss
    outs[2] = (float)exp(H);                   // perplexity
    outs[3] = (float)(cosS / 16384.0);         // selected_cosine_sim
    outs[4] = (float)(dS / (2048.0 * 2047.0)); // avg_euclidean
    outs[5] = (float)mn;                       // min_euclidean
    outs[6] = (float)sqrt(mse);                // gradient_gap
  }
}

// ---------------- launch -------------------------------------------------
extern "C" void kernel_launch(void* const* d_in, const int* in_sizes, int n_in,
                              void* d_out, int out_size, void* d_ws, size_t ws_size,
                              hipStream_t stream) {
  (void)in_sizes; (void)n_in; (void)out_size; (void)ws_size;
  const float* latent  = (const float*)d_in[0];
  const float* cb      = (const float*)d_in[1];
  const float* cmean   = (const float*)d_in[2];
  const float* cstd    = (const float*)d_in[3];
  float* out           = (float*)d_out;     // reference outputs are float32

  char* ws = (char*)d_ws;
  float* repar  = (float*)(ws + 0);
  float* rowA   = (float*)(ws + 2097152);
  float* rnorm  = (float*)(ws + 2162688);
  float* sqk    = (float*)(ws + 2228224);
  float* ncn    = (float*)(ws + 2236416);
  int*   idx    = (int*)(ws + 2244608);
  int*   hist   = (int*)(ws + 2310144);
  double* qp_mse = (double*)(ws + 2318336);
  double* qp_cos = (double*)(ws + 2351104);
  double* pp_sum = (double*)(ws + 2383872);
  u32*    pp_min = (u32*)(ws + 2392064);
  u64*    row_max = (u64*)(ws + 2396160);   // 16384 * 8 B

  float* out_q   = out;               // 4194304 floats
  float* out_idx = out + 4194304;     // 16384 floats
  float* out_scl = out + 4210688;     // 7 floats

  k_rowstats<<<64, 256, 0, stream>>>(latent, rowA, rnorm);
  k_codestats<<<KCB, 64, 0, stream>>>(cb, cmean, cstd, repar, sqk, ncn, hist, row_max);
  k_main<<<dim3(32, 256), 256, 0, stream>>>(latent, repar, rowA, sqk, row_max);
  k_argmax<<<64, 256, 0, stream>>>(row_max, idx, out_idx);
  k_quant<<<NROWS / 4, 256, 0, stream>>>(latent, repar, idx, rnorm, ncn, out_q,
                                         qp_mse, qp_cos, hist);
  k_pairs<<<dim3(32, 32), 256, 0, stream>>>(repar, sqk, pp_sum, pp_min);
  k_final<<<1, 256, 0, stream>>>(qp_mse, qp_cos, pp_sum, pp_min, hist, out_scl);
}